// Round 5
// baseline (4706.628 us; speedup 1.0000x reference)
//
#include <hip/hip_runtime.h>

// ============================================================================
// 2-layer LSTM (B=256,T=512,IN=128,H=512) + per-step linear (OUT=128).
// Persistent cooperative kernel, 256 blocks (1/CU) x 512 thr.
//  - R10: HANG-PROOF HYBRID BARRIER, ZERO RMW.
//    R9 post-mortem: its sc0 flag poll re-reads one HOT line; if sc0 loads
//    don't bypass L1 the first poll caches a stale-low flag => infinite spin.
//    (R8's sc0 restage never proved L1-bypass: cold lines, 512KB/step flushes
//    the 32KB L1 naturally.) R10 publishes each wg's step TWICE:
//      * plain store to flags_l2 (own-XCD L2)      -> fast poll, bounded 48
//      * agent-scope atomic store to flags_llc     -> fallback poll, unbounded
//    Wave 0: coalesced 32-lane sc0 poll of flags_l2 + __all; on timeout,
//    coalesced agent-scope atomic-load poll of flags_llc (atomics bypass
//    L1/L2 by construction => live, R8-proven mechanism class). No fetch_add
//    anywhere => R8's 32 serialized LLC RMWs are gone. Duration diagnoses
//    which path ran (~2.1ms fast / ~2.7ms fallback).
//  - x-prefetch under the barrier: x(i+1) global loads issue after the
//    partials-sync (hide under epilogue VALU), LDS write after release-sync.
//  - R8 retained (proven): XCD grouping via s_getreg(XCC_ID) + roster claim;
//    144KB LDS => 1 block/CU => exactly 32 blocks/XCD; plain h-stores dirty
//    in local L2; coalesced 8B sc0 restage -> XOR-swizzled LDS ->
//    conflict-free ds_read_b128 frags; h1 frags reused by both layers;
//    parity double-buffered hbuf.
//  - R6 lesson: exchange loads stay COALESCED (per-lane gather regressed 16x).
// ============================================================================

#define Bsz 256
#define Tsz 512
#define INsz 128
#define Hsz 512
#define OUTsz 128

typedef _Float16 half8 __attribute__((ext_vector_type(8)));
typedef float f32x16 __attribute__((ext_vector_type(16)));
typedef float f32x4 __attribute__((ext_vector_type(4)));
typedef unsigned int u32x4 __attribute__((ext_vector_type(4)));
typedef unsigned long long u64;

#define ROWP 520          // halves per 512-wide LDS row (out_gemm only)
#define HBU 65536u        // u32 per hbuf parity buffer (256 KB)

// dynamic LDS layout (bytes) for lstm_seq
#define H1S_B 0           // [32][512] fp16, XOR-swizzled (byte ^= row<<4)
#define H2S_B 32768       // [32][512] fp16, swizzled
#define XS_B  65536       // [32][128] fp16, swizzled (byte ^= (row&15)<<4)
#define GEXA_B 73728      // [8 blocks][32 col][36 row] f32 (layer-1 partials)
#define GEXB_B 110592     // [8 blocks][32 col][36 row] f32 (layer-2 partials)
#define LDS1_SIZE 147456  // 144KB > 80KB => hard cap 1 block/CU (roster proof)
#define LDS2_SIZE 133120  // out_gemm: As[64][520] + Bs[64][520] fp16

__device__ __forceinline__ float sigm(float v)   { return 1.0f / (1.0f + __expf(-v)); }
__device__ __forceinline__ float tanh_f(float v) { return 2.0f / (1.0f + __expf(-2.0f * v)) - 1.0f; }

__device__ __forceinline__ half8 load_w8(const float* src) {
  f32x4 a = *(const f32x4*)src;
  f32x4 b = *(const f32x4*)(src + 4);
  half8 v;
  v[0] = (_Float16)a[0]; v[1] = (_Float16)a[1]; v[2] = (_Float16)a[2]; v[3] = (_Float16)a[3];
  v[4] = (_Float16)b[0]; v[5] = (_Float16)b[1]; v[6] = (_Float16)b[2]; v[7] = (_Float16)b[3];
  return v;
}

// blk MUST be tq*4+kq: epilogue reads blocks [0..3]=tile0(i|f), [4..7]=tile1(g|o)
__device__ __forceinline__ void dump_acc(float* gex, const f32x16& acc, int blk, int nloc, int ktop) {
  #pragma unroll
  for (int r4 = 0; r4 < 4; ++r4) {
    f32x4 v;
    v[0] = acc[r4*4+0]; v[1] = acc[r4*4+1]; v[2] = acc[r4*4+2]; v[3] = acc[r4*4+3];
    // C/D layout 32x32: col=lane&31, row=(reg&3)+8*(reg>>2)+4*(lane>>5); store [col][row]
    *(f32x4*)(gex + (blk*32 + nloc)*36 + r4*8 + ktop*4) = v;
  }
}

__device__ __forceinline__ void epilogue_gates(const float* gex, int eb, int ed,
                                               float bi, float bf, float bg, float bo,
                                               float& c, float& hout) {
  float gi = bi, gf = bf, gg = bg, go = bo;
  #pragma unroll
  for (int q = 0; q < 4; ++q) {             // sum 4 K-quarter partials
    gi += gex[(q*32 + ed)*36 + eb];         // blocks 0..3, cols 0..15  = i
    gf += gex[(q*32 + ed + 16)*36 + eb];    // blocks 0..3, cols 16..31 = f
    gg += gex[((4+q)*32 + ed)*36 + eb];     // blocks 4..7, cols 0..15  = g
    go += gex[((4+q)*32 + ed + 16)*36 + eb];// blocks 4..7, cols 16..31 = o
  }
  float ii = sigm(gi), ff = sigm(gf), ta = tanh_f(gg), oo = sigm(go);
  c = ff * c + ii * ta;
  hout = oo * tanh_f(c);
}

__device__ __forceinline__ unsigned h_bits(float h) {
  union { _Float16 f; unsigned short u; } cv;
  cv.f = (_Float16)h;
  return (unsigned)cv.u;
}

// sc0 loads: bypass L1 (intent), read own XCD's L2 where plain stores land
__device__ __forceinline__ u64 load_u64_sc0(const u64* p) {
  u64 v;
  asm volatile("global_load_dwordx2 %0, %1, off sc0" : "=v"(v) : "v"(p));
  return v;
}
__device__ __forceinline__ unsigned load_u32_sc0_wait(const unsigned* p) {
  unsigned v;
  asm volatile("global_load_dword %0, %1, off sc0\n\ts_waitcnt vmcnt(0)"
               : "=v"(v) : "v"(p) : "memory");
  return v;
}

__global__ void __launch_bounds__(512, 2) lstm_seq(
    const float* __restrict__ x,
    const float* __restrict__ Wih1, const float* __restrict__ Whh1,
    const float* __restrict__ bih1, const float* __restrict__ bhh1,
    const float* __restrict__ Wih2, const float* __restrict__ Whh2,
    const float* __restrict__ bih2, const float* __restrict__ bhh2,
    unsigned int* cnt_base,
    unsigned int* __restrict__ hbuf1, unsigned int* __restrict__ hbuf2, // fp16 pairs, 2 parities
    unsigned int* __restrict__ h2hist)                                  // fp16 pairs
{
  extern __shared__ char lds[];
  float* gexA = (float*)(lds + GEXA_B);
  float* gexB = (float*)(lds + GEXB_B);
  int* s_gw = (int*)(lds + GEXA_B);   // reuse gexA space for the roster handoff

  const int tid  = threadIdx.x;
  const int lane = tid & 63;
  const int wv   = tid >> 6;     // 0..7
  const int tq   = wv & 1;       // gate tile (0: i|f, 1: g|o)
  const int kq   = wv >> 1;      // K quarter 0..3
  const int blk  = tq * 4 + kq;  // partial-block index expected by epilogue

  // ---- dynamic XCD grouping: g = physical XCD, w = roster slot ----
  if (tid == 0) {
    // s_getreg_b32 hwreg(HW_REG_XCC_ID=20, offset=0, size=4): imm = (4-1)<<11 | 0<<6 | 20
    unsigned xcd = __builtin_amdgcn_s_getreg(6164) & 7u;
    unsigned slot = __hip_atomic_fetch_add(cnt_base + 1024 + xcd, 1u,
                                           __ATOMIC_RELAXED, __HIP_MEMORY_SCOPE_AGENT);
    s_gw[0] = (int)xcd;
    s_gw[1] = (int)(slot & 31u);
  }
  __syncthreads();
  const int g = s_gw[0];             // batch group == physical XCD
  const int w = s_gw[1];             // member 0..31 (owns h-dims w*16..w*16+15)
  __syncthreads();                   // everyone read s_gw before gexA reuse

  // flag regions: 32 dwords per group, 256B group stride (no cross-group lines)
  unsigned int* flags_llc = cnt_base + g * 64;        // agent-atomic published
  unsigned int* flags_l2  = cnt_base + 512 + g * 64;  // plain-store published

  const int nloc  = lane & 31;
  const int ktop  = lane >> 5;
  const int gtype = tq * 2 + (nloc >> 4);      // 0:i 1:f 2:g 3:o
  const int wdim  = w * 16 + (nloc & 15);
  const int grow  = gtype * 512 + wdim;

  // ---- persistent weight fragments (B-operand: lane holds W[grow][k..k+8]) ----
  half8 wA[10], wB[16];
  #pragma unroll
  for (int s = 0; s < 8; ++s)
    wA[s] = load_w8(Whh1 + (size_t)grow * Hsz + (kq*8 + s)*16 + ktop*8);
  #pragma unroll
  for (int s = 0; s < 2; ++s)
    wA[8+s] = load_w8(Wih1 + (size_t)grow * INsz + kq*32 + s*16 + ktop*8);
  #pragma unroll
  for (int s = 0; s < 8; ++s)
    wB[s] = load_w8(Wih2 + (size_t)grow * Hsz + (kq*8 + s)*16 + ktop*8);
  #pragma unroll
  for (int s = 0; s < 8; ++s)
    wB[8+s] = load_w8(Whh2 + (size_t)grow * Hsz + (kq*8 + s)*16 + ktop*8);

  // ---- epilogue ownership: ed = dim-local (adjacent lanes), eb = batch ----
  const int ed = tid & 15;
  const int eb = tid >> 4;           // 0..31
  const int edim = w * 16 + ed;
  float bi1 = bih1[0*512+edim] + bhh1[0*512+edim];
  float bf1 = bih1[1*512+edim] + bhh1[1*512+edim];
  float bg1 = bih1[2*512+edim] + bhh1[2*512+edim];
  float bo1 = bih1[3*512+edim] + bhh1[3*512+edim];
  float bi2 = bih2[0*512+edim] + bhh2[0*512+edim];
  float bf2 = bih2[1*512+edim] + bhh2[1*512+edim];
  float bg2 = bih2[2*512+edim] + bhh2[2*512+edim];
  float bo2 = bih2[3*512+edim] + bhh2[3*512+edim];
  float c1 = 0.0f, c2 = 0.0f;

  const int stg_m = tid >> 4, stg_ch = tid & 15;   // x staging: row, 16B chunk
  const int xs_off = XS_B + stg_m*256 + ((stg_ch*16) ^ ((stg_m & 15) << 4));
  const int fragC = (kq*8)*32 + ktop*16;           // frag col byte base (s adds 32)
  const int xC    = kq*64 + ktop*16;               // x frag col byte base (s adds 32)

  // ---- prologue: stage x(0) ----
  *(half8*)(lds + xs_off) =
      load_w8(x + ((size_t)(g*32 + stg_m) * Tsz + 0) * INsz + stg_ch*8);

  // iteration i: layer-1 computes h1(i) (i<T), layer-2 computes h2(i-1) (i>0)
  for (int i = 0; i <= Tsz; ++i) {
    const bool doA = (i < Tsz);
    const bool doB = (i > 0);

    // parity double-buffer: write h1(i) -> [i&1], h2(i-1) -> [(i+1)&1];
    // read h1(i-1) from [(i+1)&1], h2(i-2) from [i&1].
    const u64* pb1 = (const u64*)hbuf1 + (size_t)((i+1)&1)*32768 + g*4096;
    const u64* pb2 = (const u64*)hbuf2 + (size_t)(i&1)*32768 + g*4096;
    unsigned* wb1 = hbuf1 + (i&1)*HBU;
    unsigned* wb2 = hbuf2 + ((i+1)&1)*HBU;

    // ---- issue coalesced sc0 restage loads (own-XCD L2 hits) ----
    u64 q1[8], q2[8];
    #pragma unroll
    for (int j = 0; j < 8; ++j)
      q1[j] = load_u64_sc0(pb1 + j*512 + tid);
    if (doB) {
      #pragma unroll
      for (int j = 0; j < 8; ++j)
        q2[j] = load_u64_sc0(pb2 + j*512 + tid);
    }
    asm volatile("s_waitcnt vmcnt(0)" ::: "memory");
    __builtin_amdgcn_sched_barrier(0);
    // ---- swizzled LDS writes ----
    #pragma unroll
    for (int j = 0; j < 8; ++j) {
      const int L = j*512 + tid, r = L >> 7, b = (L & 127) * 8;
      *(u64*)(lds + H1S_B + r*1024 + (b ^ (r << 4))) = q1[j];
    }
    if (doB) {
      #pragma unroll
      for (int j = 0; j < 8; ++j) {
        const int L = j*512 + tid, r = L >> 7, b = (L & 127) * 8;
        *(u64*)(lds + H2S_B + r*1024 + (b ^ (r << 4))) = q2[j];
      }
    }
    __syncthreads();   // staged h1/h2 ready (x staged during previous barrier)

    // ---- h1 fragments once from LDS (swizzled, conflict-free), reused by both layers ----
    half8 a1[8];
    #pragma unroll
    for (int s = 0; s < 8; ++s)
      a1[s] = *(const half8*)(lds + H1S_B + nloc*1024 + ((fragC + s*32) ^ (nloc << 4)));

    if (doA) {  // gates1 = Whh1 @ h1(i-1) + Wih1 @ x_i
      f32x16 acc;
      #pragma unroll
      for (int k = 0; k < 16; ++k) acc[k] = 0.0f;
      #pragma unroll
      for (int s = 0; s < 8; ++s)
        acc = __builtin_amdgcn_mfma_f32_32x32x16_f16(a1[s], wA[s], acc, 0, 0, 0);
      #pragma unroll
      for (int s = 0; s < 2; ++s) {
        half8 ax = *(const half8*)(lds + XS_B + nloc*256 + ((xC + s*32) ^ ((nloc & 15) << 4)));
        acc = __builtin_amdgcn_mfma_f32_32x32x16_f16(ax, wA[8+s], acc, 0, 0, 0);
      }
      dump_acc(gexA, acc, blk, nloc, ktop);
    }
    if (doB) {  // gates2 = Wih2 @ h1(i-1) + Whh2 @ h2(i-2)
      f32x16 acc;
      #pragma unroll
      for (int k = 0; k < 16; ++k) acc[k] = 0.0f;
      #pragma unroll
      for (int s = 0; s < 8; ++s)
        acc = __builtin_amdgcn_mfma_f32_32x32x16_f16(a1[s], wB[s], acc, 0, 0, 0);
      #pragma unroll
      for (int s = 0; s < 8; ++s) {
        half8 a2 = *(const half8*)(lds + H2S_B + nloc*1024 + ((fragC + s*32) ^ (nloc << 4)));
        acc = __builtin_amdgcn_mfma_f32_32x32x16_f16(a2, wB[8+s], acc, 0, 0, 0);
      }
      dump_acc(gexB, acc, blk, nloc, ktop);
    }
    __syncthreads();   // partials visible

    // ---- issue x(i+1) global load now; latency hides under epilogue VALU ----
    const bool doX = (i + 1 < Tsz);
    f32x4 xa, xb;
    if (doX) {
      const float* src = x + ((size_t)(g*32 + stg_m) * Tsz + (i+1)) * INsz + stg_ch*8;
      xa = *(const f32x4*)src;
      xb = *(const f32x4*)(src + 4);
    }

    // ---- epilogues: pack 2 fp16 per dword, PLAIN stores (dirty in local L2) ----
    if (doA) {
      float h;
      epilogue_gates(gexA, eb, ed, bi1, bf1, bg1, bo1, c1, h);
      unsigned lo = h_bits(h);
      unsigned hi = __shfl_down(lo, 1, 64);
      if (!(tid & 1))
        wb1[((g*32 + eb)*Hsz + w*16 + ed) >> 1] = lo | (hi << 16);
    }
    if (doB) {
      float h;
      epilogue_gates(gexB, eb, ed, bi2, bf2, bg2, bo2, c2, h);
      unsigned lo = h_bits(h);
      unsigned hi = __shfl_down(lo, 1, 64);
      if (!(tid & 1)) {
        unsigned v = lo | (hi << 16);
        wb2[((g*32 + eb)*Hsz + w*16 + ed) >> 1] = v;
        // nontemporal plain store; visibility to out_gemm via kernel boundary
        __builtin_nontemporal_store(v,
            h2hist + ((((size_t)(g*32 + eb)*Tsz + (i-1))*Hsz + w*16 + ed) >> 1));
      }
    }
    if (i == Tsz) break;   // last h2 stored; no further exchange needed

    __syncthreads();   // release: vmcnt(0) acks every wave's h plain-stores at
                       // the local L2 (and drains the x load) before publishing

    // ---- stage x(i+1) into LDS during the barrier window ----
    if (doX) {
      half8 v;
      v[0] = (_Float16)xa[0]; v[1] = (_Float16)xa[1]; v[2] = (_Float16)xa[2]; v[3] = (_Float16)xa[3];
      v[4] = (_Float16)xb[0]; v[5] = (_Float16)xb[1]; v[6] = (_Float16)xb[2]; v[7] = (_Float16)xb[3];
      *(half8*)(lds + xs_off) = v;
    }

    // ---- hybrid XCD barrier: dual publish, bounded L2 poll, LLC fallback ----
    if (tid == 0) {
      flags_l2[w] = (unsigned)(i + 1);   // plain -> dirty in own L2 (fast path)
      __hip_atomic_store(flags_llc + w, (unsigned)(i + 1),
                         __ATOMIC_RELAXED, __HIP_MEMORY_SCOPE_AGENT); // -> LLC (live path)
    }
    if (wv == 0) {
      const unsigned target = (unsigned)(i + 1);
      bool done = false;
      #pragma unroll 1
      for (int it = 0; it < 48 && !done; ++it) {
        unsigned v = (lane < 32) ? load_u32_sc0_wait(flags_l2 + lane) : target;
        done = __all((int)(v >= target));
      }
      #pragma unroll 1
      while (!done) {     // hang-proof: agent atomics bypass L1/L2 (R8-proven)
        unsigned v = (lane < 32)
            ? __hip_atomic_load(flags_llc + lane, __ATOMIC_RELAXED, __HIP_MEMORY_SCOPE_AGENT)
            : target;
        done = __all((int)(v >= target));
        if (!done) __builtin_amdgcn_s_sleep(1);
      }
    }
    __syncthreads();
  }
}

// ======================= final linear: out = H2 @ Wlin^T + b =================
__global__ void __launch_bounds__(256) out_gemm(
    const _Float16* __restrict__ h2hist, const float* __restrict__ Wlin,
    const float* __restrict__ blin, float* __restrict__ out)
{
  extern __shared__ char lds[];
  _Float16* As = (_Float16*)lds;              // [64][520]
  _Float16* Bs = (_Float16*)(lds + 66560);    // [64][520]
  const int tid = threadIdx.x;
  const int bt0 = blockIdx.x * 64;
  const int n0  = blockIdx.y * 64;

  {
    const int r = tid >> 2, k0 = (tid & 3) * 128;
    const u32x4* src = (const u32x4*)(h2hist + (size_t)(bt0 + r) * Hsz + k0);
    #pragma unroll
    for (int i = 0; i < 16; ++i)
      *(u32x4*)(As + r*ROWP + k0 + i*8) = src[i];
  }
  {
    const int n = tid >> 2, k0 = (tid & 3) * 128;
    const float* src = Wlin + (size_t)(n0 + n) * Hsz + k0;
    #pragma unroll
    for (int i = 0; i < 16; ++i)
      *(half8*)(Bs + n*ROWP + k0 + i*8) = load_w8(src + i*8);
  }
  __syncthreads();

  const int lane = tid & 63;
  const int wvid = tid >> 6;           // M-tile 0..3
  const int mrow = wvid*16 + (lane & 15);
  const int kt   = lane >> 4;          // 0..3
  f32x4 acc[4];
  #pragma unroll
  for (int nt = 0; nt < 4; ++nt) { acc[nt][0]=0; acc[nt][1]=0; acc[nt][2]=0; acc[nt][3]=0; }

  #pragma unroll
  for (int ks = 0; ks < 16; ++ks) {
    half8 a = *(const half8*)(As + mrow*ROWP + ks*32 + kt*8);
    #pragma unroll
    for (int nt = 0; nt < 4; ++nt) {
      half8 b = *(const half8*)(Bs + (nt*16 + (lane & 15))*ROWP + ks*32 + kt*8);
      acc[nt] = __builtin_amdgcn_mfma_f32_16x16x32_f16(a, b, acc[nt], 0, 0, 0);
    }
  }
  #pragma unroll
  for (int nt = 0; nt < 4; ++nt) {
    const int n = n0 + nt*16 + (lane & 15);
    const float bb = blin[n];
    #pragma unroll
    for (int r = 0; r < 4; ++r) {
      const int row = bt0 + wvid*16 + (lane >> 4)*4 + r;  // C/D: col=lane&15, row=quad*4+reg
      out[(size_t)row * OUTsz + n] = acc[nt][r] + bb;
    }
  }
}

extern "C" void kernel_launch(void* const* d_in, const int* in_sizes, int n_in,
                              void* d_out, int out_size, void* d_ws, size_t ws_size,
                              hipStream_t stream) {
  const float* x    = (const float*)d_in[0];
  const float* Wih1 = (const float*)d_in[2];
  const float* Whh1 = (const float*)d_in[3];
  const float* bih1 = (const float*)d_in[4];
  const float* bhh1 = (const float*)d_in[5];
  const float* Wih2 = (const float*)d_in[6];
  const float* Whh2 = (const float*)d_in[7];
  const float* bih2 = (const float*)d_in[8];
  const float* bhh2 = (const float*)d_in[9];
  const float* Wlin = (const float*)d_in[10];
  const float* blin = (const float*)d_in[11];
  float* out = (float*)d_out;

  char* ws = (char*)d_ws;
  // ws map: [0,2048) flags_llc (8 grp x 256B) | [2048,4096) flags_l2 |
  //         [4096,4128) roster | [8192, +512KB) hbuf1 | then hbuf2
  unsigned int* cnt    = (unsigned int*)ws;
  unsigned int* hbuf1  = (unsigned int*)(ws + 8192);      // 2 parities x 256 KB
  unsigned int* hbuf2  = (unsigned int*)(ws + 8192 + 524288);
  unsigned int* h2hist = (unsigned int*)(ws + 2097152);   // 128 MB (fp16 pairs)

  // zero flags + roster + both parities of both h-exchange buffers
  hipMemsetAsync(ws, 0, 8192 + 1048576, stream);

  hipFuncSetAttribute((const void*)lstm_seq, hipFuncAttributeMaxDynamicSharedMemorySize, LDS1_SIZE);
  hipFuncSetAttribute((const void*)out_gemm, hipFuncAttributeMaxDynamicSharedMemorySize, LDS2_SIZE);

  void* args[] = { (void*)&x, (void*)&Wih1, (void*)&Whh1, (void*)&bih1, (void*)&bhh1,
                   (void*)&Wih2, (void*)&Whh2, (void*)&bih2, (void*)&bhh2,
                   (void*)&cnt, (void*)&hbuf1, (void*)&hbuf2, (void*)&h2hist };
  hipLaunchCooperativeKernel((const void*)lstm_seq, dim3(256), dim3(512), args,
                             (unsigned int)LDS1_SIZE, stream);

  out_gemm<<<dim3(2048, 2), dim3(256), LDS2_SIZE, stream>>>((const _Float16*)h2hist, Wlin, blin, out);
}